// Round 3
// baseline (4525.925 us; speedup 1.0000x reference)
//
#include <hip/hip_runtime.h>
#include <hip/hip_bf16.h>
#include <stdint.h>

typedef unsigned long long u64;
typedef unsigned int u32;
typedef unsigned short u16;
typedef __attribute__((ext_vector_type(8))) short short8;
typedef __attribute__((ext_vector_type(16))) float float16;

#define NQ 2048
#define NT 65536
#define DIM 512
#define KNN 32
#define NC 100
#define NS 32               // slices (both paths), cand[q][slice][k]

// ---- fallback (R2) params ----
#define QT 32
#define SLICE (NT / NS)     // 2048
#define TT 256
#define KK 16
#define FCAP 32

// ---- mfma params ----
#define MQT 128             // queries per block
#define MTT 256             // trains per chunk
#define MBK 32              // k per stage
#define MSLICE 2048         // trains per block = SLICE
#define MCAP 32

// ---------------- row-norm kernel ----------------
__global__ void norm_kernel(const float* __restrict__ X, float* __restrict__ out, int nrows) {
    int row = blockIdx.x * 4 + (threadIdx.x >> 6);
    int lane = threadIdx.x & 63;
    if (row >= nrows) return;
    const float4* p = (const float4*)(X + (size_t)row * DIM);
    float4 a = p[lane];
    float4 b = p[lane + 64];
    float s = a.x*a.x + a.y*a.y + a.z*a.z + a.w*a.w
            + b.x*b.x + b.y*b.y + b.z*b.z + b.w*b.w;
    #pragma unroll
    for (int off = 32; off > 0; off >>= 1) s += __shfl_down(s, off, 64);
    if (lane == 0) out[row] = s;
}

// ---------------- bf16 hi/lo split ----------------
__global__ void split_kernel(const float* __restrict__ X, u16* __restrict__ H,
                             u16* __restrict__ L, int n4) {
    int i = blockIdx.x * 256 + threadIdx.x;
    if (i >= n4) return;
    float4 v = ((const float4*)X)[i];
    float f[4] = {v.x, v.y, v.z, v.w};
    u16 hh[4], ll[4];
    #pragma unroll
    for (int j = 0; j < 4; ++j) {
        union { __hip_bfloat16 b; u16 u; } cv;
        cv.b = __float2bfloat16(f[j]);
        hh[j] = cv.u;
        float hf = __bfloat162float(cv.b);
        cv.b = __float2bfloat16(f[j] - hf);
        ll[j] = cv.u;
    }
    ((ushort4*)H)[i] = make_ushort4(hh[0], hh[1], hh[2], hh[3]);
    ((ushort4*)L)[i] = make_ushort4(ll[0], ll[1], ll[2], ll[3]);
}

// ---------------- async global->LDS 16B ----------------
__device__ __forceinline__ void gld16(const void* g, void* l) {
    __builtin_amdgcn_global_load_lds(
        (const __attribute__((address_space(1))) u32*)g,
        (__attribute__((address_space(3))) u32*)l, 16, 0, 0);
}

// ---------------- MFMA distance + per-slice top-K ----------------
// grid: (NQ/MQT=16, NT/MSLICE=32), block 256 (4 waves)
// wave w: m_off=(w>>1)*64, n_off=(w&1)*128; wave-tile 64x128 = 2x4 of 32x32
__launch_bounds__(256, 2)
__global__ void knn_mfma(const u16* __restrict__ Qh, const u16* __restrict__ Ql,
                         const u16* __restrict__ Th, const u16* __restrict__ Tl,
                         const float* __restrict__ q2, const float* __restrict__ t2,
                         u64* __restrict__ cand) {
    __shared__ __align__(16) unsigned char smem[48 * 1024];  // tiles; aliased by buf during selection
    __shared__ u32 topkD[MQT][KNN + 1];   // +1 pad: break 32-way bank aliasing
    __shared__ u16 topkI[MQT][KNN + 1];
    __shared__ u64 kth64[MQT];
    __shared__ u32 cnt[MQT];
    __shared__ float sQ2[MQT];
    __shared__ float sT2[MTT];
    __shared__ int againF;

    u16* sAh = (u16*)smem;                // [128][32]
    u16* sAl = sAh + MQT * MBK;
    u16* sBh = sAl + MQT * MBK;           // [256][32]
    u16* sBl = sBh + MTT * MBK;
    u64* buf = (u64*)smem;                // [128][MCAP] alias (32 KB <= 48 KB)

    const int tid = threadIdx.x;
    const int lane = tid & 63;
    const int wid = tid >> 6;
    const int q0 = blockIdx.x * MQT;
    const int s0 = blockIdx.y * MSLICE;
    const int m_off = (wid >> 1) * 64;
    const int n_off = (wid & 1) * 128;
    const int l4r = lane >> 2;            // staging: row within 16-row group
    const int l4c = (lane & 3) * 8;       // staging: k-offset (elems)

    for (int i = tid; i < MQT * (KNN + 1); i += 256) {
        ((u32*)topkD)[i] = 0xFFFFFFFFu;
        ((u16*)topkI)[i] = 0xFFFFu;
    }
    if (tid < MQT) { kth64[tid] = ~0ULL; cnt[tid] = 0u; sQ2[tid] = q2[q0 + tid]; }
    if (tid == 0) againF = 0;

    for (int chunk = 0; chunk < MSLICE / MTT; ++chunk) {
        const int tb = s0 + chunk * MTT;
        float16 acc[2][4];
        #pragma unroll
        for (int mi = 0; mi < 2; ++mi)
            #pragma unroll
            for (int nj = 0; nj < 4; ++nj) acc[mi][nj] = (float16)(0.0f);

        for (int k0 = 0; k0 < DIM; k0 += MBK) {
            __syncthreads();  // previous tile consumed / previous selection done
            // stage: 48 wave-instrs (A-hi 8, A-lo 8, B-hi 16, B-lo 16)
            for (int ii = wid; ii < 48; ii += 4) {
                const u16* g; u16* ldst;
                if (ii < 16) {
                    int j = ii & 7;
                    const u16* P = (ii < 8) ? Qh : Ql;
                    u16* S = (ii < 8) ? sAh : sAl;
                    g = P + (size_t)(q0 + j * 16 + l4r) * DIM + k0 + l4c;
                    ldst = S + j * 512;
                } else {
                    int j = (ii - 16) & 15;
                    const u16* P = (ii < 32) ? Th : Tl;
                    u16* S = (ii < 32) ? sBh : sBl;
                    g = P + (size_t)(tb + j * 16 + l4r) * DIM + k0 + l4c;
                    ldst = S + j * 512;
                }
                gld16(g, ldst);
            }
            __syncthreads();  // drains vmcnt -> tiles ready

            #pragma unroll
            for (int s = 0; s < 2; ++s) {
                const int kb = s * 16 + (lane >> 5) * 8;
                short8 ah[2], al[2], bh[4], bl[4];
                #pragma unroll
                for (int mi = 0; mi < 2; ++mi) {
                    int row = m_off + mi * 32 + (lane & 31);
                    ah[mi] = *(const short8*)(const void*)&sAh[row * MBK + kb];
                    al[mi] = *(const short8*)(const void*)&sAl[row * MBK + kb];
                }
                #pragma unroll
                for (int nj = 0; nj < 4; ++nj) {
                    int row = n_off + nj * 32 + (lane & 31);
                    bh[nj] = *(const short8*)(const void*)&sBh[row * MBK + kb];
                    bl[nj] = *(const short8*)(const void*)&sBl[row * MBK + kb];
                }
                #pragma unroll
                for (int mi = 0; mi < 2; ++mi)
                    #pragma unroll
                    for (int nj = 0; nj < 4; ++nj) {
                        acc[mi][nj] = __builtin_amdgcn_mfma_f32_32x32x16_bf16(ah[mi], bh[nj], acc[mi][nj], 0, 0, 0);
                        acc[mi][nj] = __builtin_amdgcn_mfma_f32_32x32x16_bf16(ah[mi], bl[nj], acc[mi][nj], 0, 0, 0);
                        acc[mi][nj] = __builtin_amdgcn_mfma_f32_32x32x16_bf16(al[mi], bh[nj], acc[mi][nj], 0, 0, 0);
                    }
            }
        }

        // ---- selection on this 128q x 256t chunk ----
        sT2[tid] = t2[tb + tid];
        __syncthreads();  // K-loop frag reads done (buf may alias tiles), sT2 ready

        for (int g = 0; g < 2; ++g) {      // group = m-tile row (mi)
            u64 mask = 0;                   // accepted bits (nj*16+r)
            for (;;) {
                // filter: ballot-aggregated push into buf
                #pragma unroll
                for (int nj = 0; nj < 4; ++nj) {
                    #pragma unroll
                    for (int r = 0; r < 16; ++r) {
                        const int bit = nj * 16 + r;
                        const int qlo = m_off + g * 32 + (r & 3) + 8 * (r >> 2);
                        int qrow = 0; u64 key = 0; bool want = false;
                        if (!((mask >> bit) & 1)) {
                            qrow = qlo + 4 * (lane >> 5);
                            int tcol = n_off + nj * 32 + (lane & 31);
                            float d = fmaxf(sQ2[qrow] - 2.0f * acc[g][nj][r] + sT2[tcol], 0.0f);
                            key = ((u64)__float_as_uint(d) << 16) | (u64)(u32)(tb + tcol);
                            want = key < kth64[qrow];
                        }
                        u64 vote = __ballot(want);
                        if (vote) {
                            u32 lo = (u32)vote, hi = (u32)(vote >> 32);
                            u32 myBase = 0;
                            if (lane == 0 && lo)  myBase = atomicAdd(&cnt[qlo], __popc(lo));
                            if (lane == 32 && hi) myBase = atomicAdd(&cnt[qlo + 4], __popc(hi));
                            u32 b0 = (u32)__shfl((int)myBase, 0);
                            u32 b1 = (u32)__shfl((int)myBase, 32);
                            if (want) {
                                u32 half = (lane < 32) ? lo : hi;
                                u32 hl = lane & 31;
                                u32 idxin = __popc(half & ((1u << hl) - 1u));
                                u32 slot = ((lane < 32) ? b0 : b1) + idxin;
                                if (slot < MCAP) { buf[qrow * MCAP + slot] = key; mask |= (1ULL << bit); }
                            }
                        }
                    }
                }
                __syncthreads();  // buf/cnt complete
                // insert: thread tid owns query tid (eligible for this group)
                if (tid < MQT && ((tid >> 5) & 1) == g) {
                    u32 n = cnt[tid];
                    u32 m = n < MCAP ? n : MCAP;
                    for (u32 e = 0; e < m; ++e) {
                        u64 key = buf[tid * MCAP + e];
                        u64 last = ((u64)topkD[tid][KNN - 1] << 16) | topkI[tid][KNN - 1];
                        if (key < last) {
                            int p = KNN - 1;
                            while (p > 0) {
                                u64 prev = ((u64)topkD[tid][p - 1] << 16) | topkI[tid][p - 1];
                                if (prev > key) {
                                    topkD[tid][p] = topkD[tid][p - 1];
                                    topkI[tid][p] = topkI[tid][p - 1];
                                    --p;
                                } else break;
                            }
                            topkD[tid][p] = (u32)(key >> 16);
                            topkI[tid][p] = (u16)(key & 0xFFFF);
                        }
                    }
                    kth64[tid] = ((u64)topkD[tid][KNN - 1] << 16) | topkI[tid][KNN - 1];
                    if (n > MCAP) againF = 1;
                    cnt[tid] = 0u;
                }
                __syncthreads();  // insert done, againF final, kth updated
                int go = againF;
                __syncthreads();  // all reads of againF done
                if (tid == 0) againF = 0;
                if (!go) break;   // uniform
                __syncthreads();  // reset visible before next pass's insert
            }
        }
    }

    __syncthreads();
    for (int i = tid; i < MQT * KNN; i += 256) {
        int q = i >> 5, k = i & 31;
        u64 key = ((u64)topkD[q][k] << 16) | topkI[q][k];
        cand[((size_t)(q0 + q) * NS + blockIdx.y) * KNN + k] = key;
    }
}

// ---------------- fallback: fp32 distance + per-slice top-K (R2, proven) ----------------
__launch_bounds__(256, 4)
__global__ void knn_part(const float* __restrict__ Xq, const float* __restrict__ Xt,
                         const float* __restrict__ q2, const float* __restrict__ t2,
                         u64* __restrict__ cand) {
    __shared__ float sQ[KK][QT];
    __shared__ float sT[KK][TT];
    __shared__ u64 topk[QT][KNN];
    __shared__ u64 buf[QT][FCAP];
    __shared__ u64 kth64[QT];
    __shared__ u32 cnt[QT];
    __shared__ int againF;

    const int tid = threadIdx.x;
    const int q0 = blockIdx.x * QT;
    const int t0 = blockIdx.y * SLICE;
    const int tq4 = (tid >> 5) * 4;
    const int tt4 = (tid & 31) * 4;
    const int pg = tid & 63;
    const int kg = tid >> 6;
    const int qp = tid & 31;
    const int kq = tid >> 5;

    for (int i = tid; i < QT * KNN; i += 256) ((u64*)topk)[i] = ~0ULL;
    if (tid < QT) { kth64[tid] = ~0ULL; cnt[tid] = 0u; }
    if (tid == 0) againF = 0;

    float qq[4];
    #pragma unroll
    for (int i = 0; i < 4; ++i) qq[i] = q2[q0 + tq4 + i];

    for (int chunk = 0; chunk < SLICE / TT; ++chunk) {
        const int tbase = t0 + chunk * TT;
        float acc[4][8];
        #pragma unroll
        for (int i = 0; i < 4; ++i)
            #pragma unroll
            for (int j = 0; j < 8; ++j) acc[i][j] = 0.f;

        for (int k0 = 0; k0 < DIM; k0 += KK) {
            __syncthreads();
            {
                const float* Tp = Xt + (size_t)(tbase + pg * 4) * DIM + k0 + kg * 4;
                float4 r0 = *(const float4*)(Tp);
                float4 r1 = *(const float4*)(Tp + DIM);
                float4 r2 = *(const float4*)(Tp + 2 * DIM);
                float4 r3 = *(const float4*)(Tp + 3 * DIM);
                *(float4*)&sT[kg * 4 + 0][pg * 4] = make_float4(r0.x, r1.x, r2.x, r3.x);
                *(float4*)&sT[kg * 4 + 1][pg * 4] = make_float4(r0.y, r1.y, r2.y, r3.y);
                *(float4*)&sT[kg * 4 + 2][pg * 4] = make_float4(r0.z, r1.z, r2.z, r3.z);
                *(float4*)&sT[kg * 4 + 3][pg * 4] = make_float4(r0.w, r1.w, r2.w, r3.w);
            }
            {
                float2 v = *(const float2*)(Xq + (size_t)(q0 + qp) * DIM + k0 + kq * 2);
                sQ[kq * 2 + 0][qp] = v.x;
                sQ[kq * 2 + 1][qp] = v.y;
            }
            __syncthreads();
            #pragma unroll
            for (int k = 0; k < KK; ++k) {
                float4 qv = *(const float4*)&sQ[k][tq4];
                float4 ta = *(const float4*)&sT[k][tt4];
                float4 tb = *(const float4*)&sT[k][128 + tt4];
                float qa[4] = {qv.x, qv.y, qv.z, qv.w};
                float tv[8] = {ta.x, ta.y, ta.z, ta.w, tb.x, tb.y, tb.z, tb.w};
                #pragma unroll
                for (int i = 0; i < 4; ++i)
                    #pragma unroll
                    for (int j = 0; j < 8; ++j)
                        acc[i][j] = fmaf(qa[i], tv[j], acc[i][j]);
            }
        }

        float t2v[8];
        #pragma unroll
        for (int j = 0; j < 4; ++j) {
            t2v[j]     = t2[tbase + tt4 + j];
            t2v[4 + j] = t2[tbase + 128 + tt4 + j];
        }
        #pragma unroll
        for (int i = 0; i < 4; ++i)
            #pragma unroll
            for (int j = 0; j < 8; ++j)
                acc[i][j] = fmaxf((qq[i] - 2.f * acc[i][j]) + t2v[j], 0.f);

        unsigned mask = 0;
        for (;;) {
            u64 kv[4];
            #pragma unroll
            for (int i = 0; i < 4; ++i) kv[i] = kth64[tq4 + i];
            #pragma unroll
            for (int i = 0; i < 4; ++i) {
                #pragma unroll
                for (int j = 0; j < 8; ++j) {
                    unsigned b = 1u << (i * 8 + j);
                    if (mask & b) continue;
                    int tloc = (j < 4) ? (tt4 + j) : (128 + tt4 + (j - 4));
                    u64 key = ((u64)__float_as_uint(acc[i][j]) << 16) |
                              (u64)(unsigned)(tbase + tloc);
                    if (key < kv[i]) {
                        unsigned pos = atomicAdd(&cnt[tq4 + i], 1u);
                        if (pos < FCAP) { buf[tq4 + i][pos] = key; mask |= b; }
                    }
                }
            }
            __syncthreads();
            if (tid < QT) {
                unsigned n = cnt[tid];
                unsigned m = n < FCAP ? n : FCAP;
                for (unsigned e = 0; e < m; ++e) {
                    u64 key = buf[tid][e];
                    if (key < topk[tid][KNN - 1]) {
                        int p = KNN - 1;
                        while (p > 0 && topk[tid][p - 1] > key) {
                            topk[tid][p] = topk[tid][p - 1];
                            --p;
                        }
                        topk[tid][p] = key;
                    }
                }
                kth64[tid] = topk[tid][KNN - 1];
                if (n > FCAP) againF = 1;
                cnt[tid] = 0u;
            }
            __syncthreads();
            int go = againF;
            __syncthreads();
            if (tid == 0) againF = 0;
            if (!go) break;
            __syncthreads();
        }
    }

    __syncthreads();
    for (int i = tid; i < QT * KNN; i += 256) {
        int q = i >> 5, k = i & 31;
        cand[((size_t)(q0 + q) * NS + blockIdx.y) * KNN + k] = topk[q][k];
    }
}

// ---------------- merge + vote ----------------
__global__ void knn_merge(const u64* __restrict__ cand,
                          const int* __restrict__ y_train, int* __restrict__ out) {
    __shared__ u64 keys[NS * KNN];
    __shared__ u64 top[KNN];
    __shared__ int counts[NC];
    int q = blockIdx.x;
    for (int i = threadIdx.x; i < NS * KNN; i += 64)
        keys[i] = cand[(size_t)q * NS * KNN + i];
    for (int i = threadIdx.x; i < NC; i += 64) counts[i] = 0;
    if (threadIdx.x < KNN) top[threadIdx.x] = ~0ULL;
    __syncthreads();

    if (threadIdx.x == 0) {
        for (int s = 0; s < NS; ++s) {
            for (int j = 0; j < KNN; ++j) {
                u64 key = keys[s * KNN + j];
                if (key >= top[KNN - 1]) break;
                int p = KNN - 1;
                while (p > 0 && top[p - 1] > key) { top[p] = top[p - 1]; --p; }
                top[p] = key;
            }
        }
        for (int k = 0; k < KNN; ++k) {
            int idx = (int)(top[k] & 0xFFFF);
            counts[y_train[idx]]++;
        }
        int bestc = counts[0], bestl = 0;
        for (int c = 1; c < NC; ++c)
            if (counts[c] > bestc) { bestc = counts[c]; bestl = c; }
        out[q] = bestl;
    }
}

extern "C" void kernel_launch(void* const* d_in, const int* in_sizes, int n_in,
                              void* d_out, int out_size, void* d_ws, size_t ws_size,
                              hipStream_t stream) {
    const float* Xq = (const float*)d_in[0];   // [2048, 512]
    const float* Xt = (const float*)d_in[1];   // [65536, 512]
    const int*   y  = (const int*)d_in[2];     // [65536]
    int* out = (int*)d_out;                    // [2048] int32

    float* t2 = (float*)d_ws;                                   // 256 KB
    float* q2 = t2 + NT;                                        // 8 KB
    u64* cand = (u64*)(q2 + NQ);                                // 16 MB
    u16* Qh = (u16*)(cand + (size_t)NQ * NS * KNN);             // 2 MB
    u16* Ql = Qh + (size_t)NQ * DIM;                            // 2 MB
    u16* Th = Ql + (size_t)NQ * DIM;                            // 64 MB
    u16* Tl = Th + (size_t)NT * DIM;                            // 64 MB
    const size_t need = (size_t)(NT + NQ) * 4
                      + (size_t)NQ * NS * KNN * 8
                      + 2 * ((size_t)NQ * DIM + (size_t)NT * DIM) * 2;  // ~148.3 MB
    const bool use_mfma = ws_size >= need;

    norm_kernel<<<NT / 4, 256, 0, stream>>>(Xt, t2, NT);
    norm_kernel<<<NQ / 4, 256, 0, stream>>>(Xq, q2, NQ);
    if (use_mfma) {
        split_kernel<<<(NQ * DIM / 4 + 255) / 256, 256, 0, stream>>>(Xq, Qh, Ql, NQ * DIM / 4);
        split_kernel<<<(NT * DIM / 4 + 255) / 256, 256, 0, stream>>>(Xt, Th, Tl, NT * DIM / 4);
        knn_mfma<<<dim3(NQ / MQT, NT / MSLICE), 256, 0, stream>>>(Qh, Ql, Th, Tl, q2, t2, cand);
    } else {
        knn_part<<<dim3(NQ / QT, NS), 256, 0, stream>>>(Xq, Xt, q2, t2, cand);
    }
    knn_merge<<<NQ, 64, 0, stream>>>(cand, y, out);
}

// Round 4
// 3343.356 us; speedup vs baseline: 1.3537x; 1.3537x over previous
//
#include <hip/hip_runtime.h>
#include <hip/hip_bf16.h>
#include <stdint.h>

typedef unsigned long long u64;
typedef unsigned int u32;
typedef unsigned short u16;
typedef __attribute__((ext_vector_type(8))) short short8;
typedef __attribute__((ext_vector_type(16))) float float16;

#define NQ 2048
#define NT 65536
#define DIM 512
#define KNN 32
#define NC 100
#define NS 32               // slices (both paths), cand[q][slice][k]

// ---- fallback (R2) params ----
#define QT 32
#define SLICE (NT / NS)     // 2048
#define TT 256
#define KK 16
#define FCAP 32

// ---- mfma params ----
#define MQT 128             // queries per block
#define MTT 256             // trains per chunk
#define MBK 32              // k per stage
#define MSLICE 2048         // trains per block = SLICE
#define MCAP 32

// ---------------- row-norm kernel ----------------
__global__ void norm_kernel(const float* __restrict__ X, float* __restrict__ out, int nrows) {
    int row = blockIdx.x * 4 + (threadIdx.x >> 6);
    int lane = threadIdx.x & 63;
    if (row >= nrows) return;
    const float4* p = (const float4*)(X + (size_t)row * DIM);
    float4 a = p[lane];
    float4 b = p[lane + 64];
    float s = a.x*a.x + a.y*a.y + a.z*a.z + a.w*a.w
            + b.x*b.x + b.y*b.y + b.z*b.z + b.w*b.w;
    #pragma unroll
    for (int off = 32; off > 0; off >>= 1) s += __shfl_down(s, off, 64);
    if (lane == 0) out[row] = s;
}

// ---------------- bf16 hi/lo split ----------------
__global__ void split_kernel(const float* __restrict__ X, u16* __restrict__ H,
                             u16* __restrict__ L, int n4) {
    int i = blockIdx.x * 256 + threadIdx.x;
    if (i >= n4) return;
    float4 v = ((const float4*)X)[i];
    float f[4] = {v.x, v.y, v.z, v.w};
    u16 hh[4], ll[4];
    #pragma unroll
    for (int j = 0; j < 4; ++j) {
        union { __hip_bfloat16 b; u16 u; } cv;
        cv.b = __float2bfloat16(f[j]);
        hh[j] = cv.u;
        float hf = __bfloat162float(cv.b);
        cv.b = __float2bfloat16(f[j] - hf);
        ll[j] = cv.u;
    }
    ((ushort4*)H)[i] = make_ushort4(hh[0], hh[1], hh[2], hh[3]);
    ((ushort4*)L)[i] = make_ushort4(ll[0], ll[1], ll[2], ll[3]);
}

// ---------------- async global->LDS 16B ----------------
__device__ __forceinline__ void gld16(const void* g, void* l) {
    __builtin_amdgcn_global_load_lds(
        (const __attribute__((address_space(1))) u32*)g,
        (__attribute__((address_space(3))) u32*)l, 16, 0, 0);
}

// ---------------- MFMA distance + per-slice top-K ----------------
// grid: (NQ/MQT=16, NT/MSLICE=32), block 256 (4 waves)
// wave w: m_off=(w>>1)*64, n_off=(w&1)*128; wave-tile 64x128 = 2x4 of 32x32
__launch_bounds__(256, 2)
__global__ void knn_mfma(const u16* __restrict__ Qh, const u16* __restrict__ Ql,
                         const u16* __restrict__ Th, const u16* __restrict__ Tl,
                         const float* __restrict__ q2, const float* __restrict__ t2,
                         u64* __restrict__ cand) {
    __shared__ __align__(16) unsigned char smem[48 * 1024];  // tiles; aliased by buf during selection
    __shared__ u32 topkD[MQT][KNN + 1];   // +1 pad: break 32-way bank aliasing
    __shared__ u16 topkI[MQT][KNN + 1];
    __shared__ u64 kth64[MQT];
    __shared__ u32 cnt[MQT];
    __shared__ float sQ2[MQT];
    __shared__ float sT2[MTT];
    __shared__ int againF;

    u16* sAh = (u16*)smem;                // [128][32]
    u16* sAl = sAh + MQT * MBK;
    u16* sBh = sAl + MQT * MBK;           // [256][32]
    u16* sBl = sBh + MTT * MBK;
    u64* buf = (u64*)smem;                // [128][MCAP] alias (32 KB <= 48 KB)

    const int tid = threadIdx.x;
    const int lane = tid & 63;
    const int wid = tid >> 6;
    const int q0 = blockIdx.x * MQT;
    const int s0 = blockIdx.y * MSLICE;
    const int m_off = (wid >> 1) * 64;
    const int n_off = (wid & 1) * 128;
    const int l4r = lane >> 2;            // staging: row within 16-row group
    const int l4c = (lane & 3) * 8;       // staging: k-offset (elems)

    for (int i = tid; i < MQT * (KNN + 1); i += 256) {
        ((u32*)topkD)[i] = 0xFFFFFFFFu;
        ((u16*)topkI)[i] = 0xFFFFu;
    }
    if (tid < MQT) { kth64[tid] = ~0ULL; cnt[tid] = 0u; sQ2[tid] = q2[q0 + tid]; }
    if (tid == 0) againF = 0;

    for (int chunk = 0; chunk < MSLICE / MTT; ++chunk) {
        const int tb = s0 + chunk * MTT;
        float16 acc[2][4];
        #pragma unroll
        for (int mi = 0; mi < 2; ++mi)
            #pragma unroll
            for (int nj = 0; nj < 4; ++nj) acc[mi][nj] = (float16)(0.0f);

        for (int k0 = 0; k0 < DIM; k0 += MBK) {
            __syncthreads();  // previous tile consumed / previous selection done
            // stage: 48 wave-instrs (A-hi 8, A-lo 8, B-hi 16, B-lo 16)
            for (int ii = wid; ii < 48; ii += 4) {
                const u16* g; u16* ldst;
                if (ii < 16) {
                    int j = ii & 7;
                    const u16* P = (ii < 8) ? Qh : Ql;
                    u16* S = (ii < 8) ? sAh : sAl;
                    g = P + (size_t)(q0 + j * 16 + l4r) * DIM + k0 + l4c;
                    ldst = S + j * 512;
                } else {
                    int j = (ii - 16) & 15;
                    const u16* P = (ii < 32) ? Th : Tl;
                    u16* S = (ii < 32) ? sBh : sBl;
                    g = P + (size_t)(tb + j * 16 + l4r) * DIM + k0 + l4c;
                    ldst = S + j * 512;
                }
                gld16(g, ldst);
            }
            __syncthreads();  // drains vmcnt -> tiles ready

            #pragma unroll
            for (int s = 0; s < 2; ++s) {
                const int kb = s * 16 + (lane >> 5) * 8;
                short8 ah[2], al[2];
                #pragma unroll
                for (int mi = 0; mi < 2; ++mi) {
                    int row = m_off + mi * 32 + (lane & 31);
                    ah[mi] = *(const short8*)(const void*)&sAh[row * MBK + kb];
                    al[mi] = *(const short8*)(const void*)&sAl[row * MBK + kb];
                }
                #pragma unroll
                for (int nj = 0; nj < 4; ++nj) {
                    int row = n_off + nj * 32 + (lane & 31);
                    short8 bh = *(const short8*)(const void*)&sBh[row * MBK + kb];
                    short8 bl = *(const short8*)(const void*)&sBl[row * MBK + kb];
                    #pragma unroll
                    for (int mi = 0; mi < 2; ++mi) {
                        acc[mi][nj] = __builtin_amdgcn_mfma_f32_32x32x16_bf16(ah[mi], bh, acc[mi][nj], 0, 0, 0);
                        acc[mi][nj] = __builtin_amdgcn_mfma_f32_32x32x16_bf16(ah[mi], bl, acc[mi][nj], 0, 0, 0);
                        acc[mi][nj] = __builtin_amdgcn_mfma_f32_32x32x16_bf16(al[mi], bh, acc[mi][nj], 0, 0, 0);
                    }
                }
            }
        }

        // ---- selection on this 128q x 256t chunk ----
        sT2[tid] = t2[tb + tid];
        __syncthreads();  // K-loop frag reads done (buf may alias tiles), sT2 ready

        #pragma unroll   // CRITICAL: g must be a compile-time constant so acc[]
        for (int g = 0; g < 2; ++g) {   // stays SROA-able (dynamic index -> scratch spill, R3's 8.5 GB WRITE_SIZE)
            u64 mask = 0;                   // accepted bits (nj*16+r)
            for (;;) {
                // filter: ballot-aggregated push into buf
                #pragma unroll
                for (int nj = 0; nj < 4; ++nj) {
                    #pragma unroll
                    for (int r = 0; r < 16; ++r) {
                        const int bit = nj * 16 + r;
                        const int qlo = m_off + g * 32 + (r & 3) + 8 * (r >> 2);
                        int qrow = 0; u64 key = 0; bool want = false;
                        if (!((mask >> bit) & 1)) {
                            qrow = qlo + 4 * (lane >> 5);
                            int tcol = n_off + nj * 32 + (lane & 31);
                            float d = fmaxf(sQ2[qrow] - 2.0f * acc[g][nj][r] + sT2[tcol], 0.0f);
                            key = ((u64)__float_as_uint(d) << 16) | (u64)(u32)(tb + tcol);
                            want = key < kth64[qrow];
                        }
                        u64 vote = __ballot(want);
                        if (vote) {
                            u32 lo = (u32)vote, hi = (u32)(vote >> 32);
                            u32 myBase = 0;
                            if (lane == 0 && lo)  myBase = atomicAdd(&cnt[qlo], __popc(lo));
                            if (lane == 32 && hi) myBase = atomicAdd(&cnt[qlo + 4], __popc(hi));
                            u32 b0 = (u32)__shfl((int)myBase, 0);
                            u32 b1 = (u32)__shfl((int)myBase, 32);
                            if (want) {
                                u32 half = (lane < 32) ? lo : hi;
                                u32 hl = lane & 31;
                                u32 idxin = __popc(half & ((1u << hl) - 1u));
                                u32 slot = ((lane < 32) ? b0 : b1) + idxin;
                                if (slot < MCAP) { buf[qrow * MCAP + slot] = key; mask |= (1ULL << bit); }
                            }
                        }
                    }
                }
                __syncthreads();  // buf/cnt complete
                // insert: thread tid owns query tid (eligible for this group)
                if (tid < MQT && ((tid >> 5) & 1) == g) {
                    u32 n = cnt[tid];
                    u32 m = n < MCAP ? n : MCAP;
                    for (u32 e = 0; e < m; ++e) {
                        u64 key = buf[tid * MCAP + e];
                        u64 last = ((u64)topkD[tid][KNN - 1] << 16) | topkI[tid][KNN - 1];
                        if (key < last) {
                            int p = KNN - 1;
                            while (p > 0) {
                                u64 prev = ((u64)topkD[tid][p - 1] << 16) | topkI[tid][p - 1];
                                if (prev > key) {
                                    topkD[tid][p] = topkD[tid][p - 1];
                                    topkI[tid][p] = topkI[tid][p - 1];
                                    --p;
                                } else break;
                            }
                            topkD[tid][p] = (u32)(key >> 16);
                            topkI[tid][p] = (u16)(key & 0xFFFF);
                        }
                    }
                    kth64[tid] = ((u64)topkD[tid][KNN - 1] << 16) | topkI[tid][KNN - 1];
                    if (n > MCAP) againF = 1;
                    cnt[tid] = 0u;
                }
                __syncthreads();  // insert done, againF final, kth updated
                int go = againF;
                __syncthreads();  // all reads of againF done
                if (tid == 0) againF = 0;
                if (!go) break;   // uniform
                __syncthreads();  // reset visible before next pass's insert
            }
        }
    }

    __syncthreads();
    for (int i = tid; i < MQT * KNN; i += 256) {
        int q = i >> 5, k = i & 31;
        u64 key = ((u64)topkD[q][k] << 16) | topkI[q][k];
        cand[((size_t)(q0 + q) * NS + blockIdx.y) * KNN + k] = key;
    }
}

// ---------------- fallback: fp32 distance + per-slice top-K (R2, proven) ----------------
__launch_bounds__(256, 4)
__global__ void knn_part(const float* __restrict__ Xq, const float* __restrict__ Xt,
                         const float* __restrict__ q2, const float* __restrict__ t2,
                         u64* __restrict__ cand) {
    __shared__ float sQ[KK][QT];
    __shared__ float sT[KK][TT];
    __shared__ u64 topk[QT][KNN];
    __shared__ u64 buf[QT][FCAP];
    __shared__ u64 kth64[QT];
    __shared__ u32 cnt[QT];
    __shared__ int againF;

    const int tid = threadIdx.x;
    const int q0 = blockIdx.x * QT;
    const int t0 = blockIdx.y * SLICE;
    const int tq4 = (tid >> 5) * 4;
    const int tt4 = (tid & 31) * 4;
    const int pg = tid & 63;
    const int kg = tid >> 6;
    const int qp = tid & 31;
    const int kq = tid >> 5;

    for (int i = tid; i < QT * KNN; i += 256) ((u64*)topk)[i] = ~0ULL;
    if (tid < QT) { kth64[tid] = ~0ULL; cnt[tid] = 0u; }
    if (tid == 0) againF = 0;

    float qq[4];
    #pragma unroll
    for (int i = 0; i < 4; ++i) qq[i] = q2[q0 + tq4 + i];

    for (int chunk = 0; chunk < SLICE / TT; ++chunk) {
        const int tbase = t0 + chunk * TT;
        float acc[4][8];
        #pragma unroll
        for (int i = 0; i < 4; ++i)
            #pragma unroll
            for (int j = 0; j < 8; ++j) acc[i][j] = 0.f;

        for (int k0 = 0; k0 < DIM; k0 += KK) {
            __syncthreads();
            {
                const float* Tp = Xt + (size_t)(tbase + pg * 4) * DIM + k0 + kg * 4;
                float4 r0 = *(const float4*)(Tp);
                float4 r1 = *(const float4*)(Tp + DIM);
                float4 r2 = *(const float4*)(Tp + 2 * DIM);
                float4 r3 = *(const float4*)(Tp + 3 * DIM);
                *(float4*)&sT[kg * 4 + 0][pg * 4] = make_float4(r0.x, r1.x, r2.x, r3.x);
                *(float4*)&sT[kg * 4 + 1][pg * 4] = make_float4(r0.y, r1.y, r2.y, r3.y);
                *(float4*)&sT[kg * 4 + 2][pg * 4] = make_float4(r0.z, r1.z, r2.z, r3.z);
                *(float4*)&sT[kg * 4 + 3][pg * 4] = make_float4(r0.w, r1.w, r2.w, r3.w);
            }
            {
                float2 v = *(const float2*)(Xq + (size_t)(q0 + qp) * DIM + k0 + kq * 2);
                sQ[kq * 2 + 0][qp] = v.x;
                sQ[kq * 2 + 1][qp] = v.y;
            }
            __syncthreads();
            #pragma unroll
            for (int k = 0; k < KK; ++k) {
                float4 qv = *(const float4*)&sQ[k][tq4];
                float4 ta = *(const float4*)&sT[k][tt4];
                float4 tb = *(const float4*)&sT[k][128 + tt4];
                float qa[4] = {qv.x, qv.y, qv.z, qv.w};
                float tv[8] = {ta.x, ta.y, ta.z, ta.w, tb.x, tb.y, tb.z, tb.w};
                #pragma unroll
                for (int i = 0; i < 4; ++i)
                    #pragma unroll
                    for (int j = 0; j < 8; ++j)
                        acc[i][j] = fmaf(qa[i], tv[j], acc[i][j]);
            }
        }

        float t2v[8];
        #pragma unroll
        for (int j = 0; j < 4; ++j) {
            t2v[j]     = t2[tbase + tt4 + j];
            t2v[4 + j] = t2[tbase + 128 + tt4 + j];
        }
        #pragma unroll
        for (int i = 0; i < 4; ++i)
            #pragma unroll
            for (int j = 0; j < 8; ++j)
                acc[i][j] = fmaxf((qq[i] - 2.f * acc[i][j]) + t2v[j], 0.f);

        unsigned mask = 0;
        for (;;) {
            u64 kv[4];
            #pragma unroll
            for (int i = 0; i < 4; ++i) kv[i] = kth64[tq4 + i];
            #pragma unroll
            for (int i = 0; i < 4; ++i) {
                #pragma unroll
                for (int j = 0; j < 8; ++j) {
                    unsigned b = 1u << (i * 8 + j);
                    if (mask & b) continue;
                    int tloc = (j < 4) ? (tt4 + j) : (128 + tt4 + (j - 4));
                    u64 key = ((u64)__float_as_uint(acc[i][j]) << 16) |
                              (u64)(unsigned)(tbase + tloc);
                    if (key < kv[i]) {
                        unsigned pos = atomicAdd(&cnt[tq4 + i], 1u);
                        if (pos < FCAP) { buf[tq4 + i][pos] = key; mask |= b; }
                    }
                }
            }
            __syncthreads();
            if (tid < QT) {
                unsigned n = cnt[tid];
                unsigned m = n < FCAP ? n : FCAP;
                for (unsigned e = 0; e < m; ++e) {
                    u64 key = buf[tid][e];
                    if (key < topk[tid][KNN - 1]) {
                        int p = KNN - 1;
                        while (p > 0 && topk[tid][p - 1] > key) {
                            topk[tid][p] = topk[tid][p - 1];
                            --p;
                        }
                        topk[tid][p] = key;
                    }
                }
                kth64[tid] = topk[tid][KNN - 1];
                if (n > FCAP) againF = 1;
                cnt[tid] = 0u;
            }
            __syncthreads();
            int go = againF;
            __syncthreads();
            if (tid == 0) againF = 0;
            if (!go) break;
            __syncthreads();
        }
    }

    __syncthreads();
    for (int i = tid; i < QT * KNN; i += 256) {
        int q = i >> 5, k = i & 31;
        cand[((size_t)(q0 + q) * NS + blockIdx.y) * KNN + k] = topk[q][k];
    }
}

// ---------------- merge + vote ----------------
__global__ void knn_merge(const u64* __restrict__ cand,
                          const int* __restrict__ y_train, int* __restrict__ out) {
    __shared__ u64 keys[NS * KNN];
    __shared__ u64 top[KNN];
    __shared__ int counts[NC];
    int q = blockIdx.x;
    for (int i = threadIdx.x; i < NS * KNN; i += 64)
        keys[i] = cand[(size_t)q * NS * KNN + i];
    for (int i = threadIdx.x; i < NC; i += 64) counts[i] = 0;
    if (threadIdx.x < KNN) top[threadIdx.x] = ~0ULL;
    __syncthreads();

    if (threadIdx.x == 0) {
        for (int s = 0; s < NS; ++s) {
            for (int j = 0; j < KNN; ++j) {
                u64 key = keys[s * KNN + j];
                if (key >= top[KNN - 1]) break;
                int p = KNN - 1;
                while (p > 0 && top[p - 1] > key) { top[p] = top[p - 1]; --p; }
                top[p] = key;
            }
        }
        for (int k = 0; k < KNN; ++k) {
            int idx = (int)(top[k] & 0xFFFF);
            counts[y_train[idx]]++;
        }
        int bestc = counts[0], bestl = 0;
        for (int c = 1; c < NC; ++c)
            if (counts[c] > bestc) { bestc = counts[c]; bestl = c; }
        out[q] = bestl;
    }
}

extern "C" void kernel_launch(void* const* d_in, const int* in_sizes, int n_in,
                              void* d_out, int out_size, void* d_ws, size_t ws_size,
                              hipStream_t stream) {
    const float* Xq = (const float*)d_in[0];   // [2048, 512]
    const float* Xt = (const float*)d_in[1];   // [65536, 512]
    const int*   y  = (const int*)d_in[2];     // [65536]
    int* out = (int*)d_out;                    // [2048] int32

    float* t2 = (float*)d_ws;                                   // 256 KB
    float* q2 = t2 + NT;                                        // 8 KB
    u64* cand = (u64*)(q2 + NQ);                                // 16 MB
    u16* Qh = (u16*)(cand + (size_t)NQ * NS * KNN);             // 2 MB
    u16* Ql = Qh + (size_t)NQ * DIM;                            // 2 MB
    u16* Th = Ql + (size_t)NQ * DIM;                            // 64 MB
    u16* Tl = Th + (size_t)NT * DIM;                            // 64 MB
    const size_t need = (size_t)(NT + NQ) * 4
                      + (size_t)NQ * NS * KNN * 8
                      + 2 * ((size_t)NQ * DIM + (size_t)NT * DIM) * 2;  // ~148.3 MB
    const bool use_mfma = ws_size >= need;

    norm_kernel<<<NT / 4, 256, 0, stream>>>(Xt, t2, NT);
    norm_kernel<<<NQ / 4, 256, 0, stream>>>(Xq, q2, NQ);
    if (use_mfma) {
        split_kernel<<<(NQ * DIM / 4 + 255) / 256, 256, 0, stream>>>(Xq, Qh, Ql, NQ * DIM / 4);
        split_kernel<<<(NT * DIM / 4 + 255) / 256, 256, 0, stream>>>(Xt, Th, Tl, NT * DIM / 4);
        knn_mfma<<<dim3(NQ / MQT, NT / MSLICE), 256, 0, stream>>>(Qh, Ql, Th, Tl, q2, t2, cand);
    } else {
        knn_part<<<dim3(NQ / QT, NS), 256, 0, stream>>>(Xq, Xt, q2, t2, cand);
    }
    knn_merge<<<NQ, 64, 0, stream>>>(cand, y, out);
}

// Round 5
// 2577.319 us; speedup vs baseline: 1.7561x; 1.2972x over previous
//
#include <hip/hip_runtime.h>
#include <hip/hip_bf16.h>
#include <stdint.h>

typedef unsigned long long u64;
typedef unsigned int u32;
typedef unsigned short u16;
typedef __attribute__((ext_vector_type(8))) short short8;
typedef __attribute__((ext_vector_type(16))) float float16;

#define NQ 2048
#define NT 65536
#define DIM 512
#define KNN 32
#define NC 100
#define NS 32               // slices (both paths), cand[q][slice][k]

// ---- fallback (R2) params ----
#define QT 32
#define SLICE (NT / NS)     // 2048
#define TT 256
#define KK 16
#define FCAP 32

// ---- prepass params (fp32, trains 0..2047 subsample) ----
#define PQT 32
#define PTT 256
#define PSLICE 512
#define NTPRE 2048

// ---- mfma params ----
#define MQT 128             // queries per block
#define MTT 256             // trains per chunk
#define MBK 32              // k per stage
#define MSLICE 2048         // trains per block = SLICE
#define MCAP 32

// ---------------- row-norm kernel ----------------
__global__ void norm_kernel(const float* __restrict__ X, float* __restrict__ out, int nrows) {
    int row = blockIdx.x * 4 + (threadIdx.x >> 6);
    int lane = threadIdx.x & 63;
    if (row >= nrows) return;
    const float4* p = (const float4*)(X + (size_t)row * DIM);
    float4 a = p[lane];
    float4 b = p[lane + 64];
    float s = a.x*a.x + a.y*a.y + a.z*a.z + a.w*a.w
            + b.x*b.x + b.y*b.y + b.z*b.z + b.w*b.w;
    #pragma unroll
    for (int off = 32; off > 0; off >>= 1) s += __shfl_down(s, off, 64);
    if (lane == 0) out[row] = s;
}

// ---------------- bf16 hi/lo split ----------------
__global__ void split_kernel(const float* __restrict__ X, u16* __restrict__ H,
                             u16* __restrict__ L, int n4) {
    int i = blockIdx.x * 256 + threadIdx.x;
    if (i >= n4) return;
    float4 v = ((const float4*)X)[i];
    float f[4] = {v.x, v.y, v.z, v.w};
    u16 hh[4], ll[4];
    #pragma unroll
    for (int j = 0; j < 4; ++j) {
        union { __hip_bfloat16 b; u16 u; } cv;
        cv.b = __float2bfloat16(f[j]);
        hh[j] = cv.u;
        float hf = __bfloat162float(cv.b);
        cv.b = __float2bfloat16(f[j] - hf);
        ll[j] = cv.u;
    }
    ((ushort4*)H)[i] = make_ushort4(hh[0], hh[1], hh[2], hh[3]);
    ((ushort4*)L)[i] = make_ushort4(ll[0], ll[1], ll[2], ll[3]);
}

// ---------------- prepass: exact 32nd-smallest distance over trains 0..2047 ----------------
// grid: (NQ/PQT=64, NTPRE/PSLICE=4). seed[q] = min over blocks of (32nd-smallest d2 bits).
// Subset property: 32nd-smallest over ANY train subset >= global 32nd -> valid filter UB.
__launch_bounds__(256, 2)
__global__ void knn_prepass(const float* __restrict__ Xq, const float* __restrict__ Xt,
                            const float* __restrict__ q2, const float* __restrict__ t2,
                            u32* __restrict__ seed) {
    __shared__ float sQ[KK][PQT];          // 2 KB
    __shared__ float sT[KK][PTT];          // 16 KB
    __shared__ float sD[PQT][PTT + 1];     // 32.1 KB (padded rows)
    __shared__ u32 topk[PQT][KNN + 1];     // 4.2 KB (dist bits only)

    const int tid = threadIdx.x;
    const int q0 = blockIdx.x * PQT;
    const int t0p = blockIdx.y * PSLICE;
    const int tq4 = (tid >> 5) * 4;
    const int tt4 = (tid & 31) * 4;
    const int pg = tid & 63;
    const int kg = tid >> 6;
    const int qp = tid & 31;
    const int kq = tid >> 5;

    for (int i = tid; i < PQT * (KNN + 1); i += 256) ((u32*)topk)[i] = 0xFFFFFFFFu;
    u32 kth = 0xFFFFFFFFu;   // register cache (selection threads)

    float qq[4];
    #pragma unroll
    for (int i = 0; i < 4; ++i) qq[i] = q2[q0 + tq4 + i];

    for (int chunk = 0; chunk < PSLICE / PTT; ++chunk) {
        const int tbase = t0p + chunk * PTT;
        float acc[4][8];
        #pragma unroll
        for (int i = 0; i < 4; ++i)
            #pragma unroll
            for (int j = 0; j < 8; ++j) acc[i][j] = 0.f;

        for (int k0 = 0; k0 < DIM; k0 += KK) {
            __syncthreads();   // protects sQ/sT and previous selection's sD reads
            {
                const float* Tp = Xt + (size_t)(tbase + pg * 4) * DIM + k0 + kg * 4;
                float4 r0 = *(const float4*)(Tp);
                float4 r1 = *(const float4*)(Tp + DIM);
                float4 r2 = *(const float4*)(Tp + 2 * DIM);
                float4 r3 = *(const float4*)(Tp + 3 * DIM);
                *(float4*)&sT[kg * 4 + 0][pg * 4] = make_float4(r0.x, r1.x, r2.x, r3.x);
                *(float4*)&sT[kg * 4 + 1][pg * 4] = make_float4(r0.y, r1.y, r2.y, r3.y);
                *(float4*)&sT[kg * 4 + 2][pg * 4] = make_float4(r0.z, r1.z, r2.z, r3.z);
                *(float4*)&sT[kg * 4 + 3][pg * 4] = make_float4(r0.w, r1.w, r2.w, r3.w);
            }
            {
                float2 v = *(const float2*)(Xq + (size_t)(q0 + qp) * DIM + k0 + kq * 2);
                sQ[kq * 2 + 0][qp] = v.x;
                sQ[kq * 2 + 1][qp] = v.y;
            }
            __syncthreads();
            #pragma unroll
            for (int k = 0; k < KK; ++k) {
                float4 qv = *(const float4*)&sQ[k][tq4];
                float4 ta = *(const float4*)&sT[k][tt4];
                float4 tb = *(const float4*)&sT[k][128 + tt4];
                float qa[4] = {qv.x, qv.y, qv.z, qv.w};
                float tv[8] = {ta.x, ta.y, ta.z, ta.w, tb.x, tb.y, tb.z, tb.w};
                #pragma unroll
                for (int i = 0; i < 4; ++i)
                    #pragma unroll
                    for (int j = 0; j < 8; ++j)
                        acc[i][j] = fmaf(qa[i], tv[j], acc[i][j]);
            }
        }

        #pragma unroll
        for (int i = 0; i < 4; ++i)
            #pragma unroll
            for (int j = 0; j < 8; ++j) {
                int t = (j < 4) ? (tt4 + j) : (128 + tt4 + (j - 4));
                sD[tq4 + i][t] = fmaxf((qq[i] - 2.f * acc[i][j]) + t2[tbase + t], 0.f);
            }
        __syncthreads();

        // serial scan selection (R1-style); flood here is small (512 trains) and local
        if (tid < PQT) {
            for (int t = 0; t < PTT; ++t) {
                u32 d = __float_as_uint(sD[tid][t]);
                if (d < kth) {
                    int p = KNN - 1;
                    while (p > 0 && topk[tid][p - 1] > d) {
                        topk[tid][p] = topk[tid][p - 1];
                        --p;
                    }
                    topk[tid][p] = d;
                    kth = topk[tid][KNN - 1];
                }
            }
        }
        // next chunk's first barrier orders selection before sD is overwritten
    }
    if (tid < PQT) atomicMin(&seed[q0 + tid], kth);
}

// ---------------- async global->LDS 16B ----------------
__device__ __forceinline__ void gld16(const void* g, void* l) {
    __builtin_amdgcn_global_load_lds(
        (const __attribute__((address_space(1))) u32*)g,
        (__attribute__((address_space(3))) u32*)l, 16, 0, 0);
}

// ---------------- MFMA distance + per-slice top-K ----------------
// grid: (NT/MSLICE=32, NQ/MQT=16)  [x=slice so same-slice blocks share an XCD: id%8 = x%8]
// wave w: m_off=(w>>1)*64, n_off=(w&1)*128; wave-tile 64x128 = 2x4 of 32x32
__launch_bounds__(256, 2)
__global__ void knn_mfma(const u16* __restrict__ Qh, const u16* __restrict__ Ql,
                         const u16* __restrict__ Th, const u16* __restrict__ Tl,
                         const float* __restrict__ q2, const float* __restrict__ t2,
                         const u32* __restrict__ seed, u64* __restrict__ cand) {
    __shared__ __align__(16) unsigned char smem[48 * 1024];  // tiles; aliased by buf during selection
    __shared__ u32 topkD[MQT][KNN + 1];   // +1 pad: break 32-way bank aliasing
    __shared__ u16 topkI[MQT][KNN + 1];
    __shared__ u64 kth64[MQT];
    __shared__ u32 cnt[MQT];
    __shared__ float sQ2[MQT];
    __shared__ float sT2[MTT];
    __shared__ int againF;

    u16* sAh = (u16*)smem;                // [128][32]
    u16* sAl = sAh + MQT * MBK;
    u16* sBh = sAl + MQT * MBK;           // [256][32]
    u16* sBl = sBh + MTT * MBK;
    u64* buf = (u64*)smem;                // [128][MCAP] alias (32 KB <= 48 KB)

    const int tid = threadIdx.x;
    const int lane = tid & 63;
    const int wid = tid >> 6;
    const int q0 = blockIdx.y * MQT;
    const int s0 = blockIdx.x * MSLICE;
    const int m_off = (wid >> 1) * 64;
    const int n_off = (wid & 1) * 128;
    const int l4r = lane >> 2;            // staging: row within 16-row group
    const int l4c = (lane & 3) * 8;       // staging: k-offset (elems)

    for (int i = tid; i < MQT * (KNN + 1); i += 256) {
        ((u32*)topkD)[i] = 0xFFFFFFFFu;
        ((u16*)topkI)[i] = 0xFFFFu;
    }
    // Seeded threshold: (seed_d+1)<<16 admits every key with dist <= seed_d.
    // seed_d >= global 32nd-NN dist => no true top-32 member is ever rejected.
    u64 seedkey = ~0ULL;
    if (tid < MQT) {
        seedkey = ((u64)seed[q0 + tid] + 1) << 16;
        kth64[tid] = seedkey;
        cnt[tid] = 0u;
        sQ2[tid] = q2[q0 + tid];
    }
    if (tid == 0) againF = 0;

    for (int chunk = 0; chunk < MSLICE / MTT; ++chunk) {
        const int tb = s0 + chunk * MTT;
        float16 acc[2][4];
        #pragma unroll
        for (int mi = 0; mi < 2; ++mi)
            #pragma unroll
            for (int nj = 0; nj < 4; ++nj) acc[mi][nj] = (float16)(0.0f);

        for (int k0 = 0; k0 < DIM; k0 += MBK) {
            __syncthreads();  // previous tile consumed / previous selection done
            // stage: 48 wave-instrs (A-hi 8, A-lo 8, B-hi 16, B-lo 16)
            for (int ii = wid; ii < 48; ii += 4) {
                const u16* g; u16* ldst;
                if (ii < 16) {
                    int j = ii & 7;
                    const u16* P = (ii < 8) ? Qh : Ql;
                    u16* S = (ii < 8) ? sAh : sAl;
                    g = P + (size_t)(q0 + j * 16 + l4r) * DIM + k0 + l4c;
                    ldst = S + j * 512;
                } else {
                    int j = (ii - 16) & 15;
                    const u16* P = (ii < 32) ? Th : Tl;
                    u16* S = (ii < 32) ? sBh : sBl;
                    g = P + (size_t)(tb + j * 16 + l4r) * DIM + k0 + l4c;
                    ldst = S + j * 512;
                }
                gld16(g, ldst);
            }
            __syncthreads();  // drains vmcnt -> tiles ready

            #pragma unroll
            for (int s = 0; s < 2; ++s) {
                const int kb = s * 16 + (lane >> 5) * 8;
                short8 ah[2], al[2];
                #pragma unroll
                for (int mi = 0; mi < 2; ++mi) {
                    int row = m_off + mi * 32 + (lane & 31);
                    ah[mi] = *(const short8*)(const void*)&sAh[row * MBK + kb];
                    al[mi] = *(const short8*)(const void*)&sAl[row * MBK + kb];
                }
                #pragma unroll
                for (int nj = 0; nj < 4; ++nj) {
                    int row = n_off + nj * 32 + (lane & 31);
                    short8 bh = *(const short8*)(const void*)&sBh[row * MBK + kb];
                    short8 bl = *(const short8*)(const void*)&sBl[row * MBK + kb];
                    #pragma unroll
                    for (int mi = 0; mi < 2; ++mi) {
                        acc[mi][nj] = __builtin_amdgcn_mfma_f32_32x32x16_bf16(ah[mi], bh, acc[mi][nj], 0, 0, 0);
                        acc[mi][nj] = __builtin_amdgcn_mfma_f32_32x32x16_bf16(ah[mi], bl, acc[mi][nj], 0, 0, 0);
                        acc[mi][nj] = __builtin_amdgcn_mfma_f32_32x32x16_bf16(al[mi], bh, acc[mi][nj], 0, 0, 0);
                    }
                }
            }
        }

        // ---- selection on this 128q x 256t chunk ----
        sT2[tid] = t2[tb + tid];
        __syncthreads();  // K-loop frag reads done (buf may alias tiles), sT2 ready

        #pragma unroll   // CRITICAL: g must be compile-time so acc[] stays SROA-able
        for (int g = 0; g < 2; ++g) {
            u64 mask = 0;                   // accepted bits (nj*16+r)
            for (;;) {
                // filter: ballot-aggregated push into buf (mostly empty now, thanks to seed)
                #pragma unroll
                for (int nj = 0; nj < 4; ++nj) {
                    #pragma unroll
                    for (int r = 0; r < 16; ++r) {
                        const int bit = nj * 16 + r;
                        const int qlo = m_off + g * 32 + (r & 3) + 8 * (r >> 2);
                        int qrow = 0; u64 key = 0; bool want = false;
                        if (!((mask >> bit) & 1)) {
                            qrow = qlo + 4 * (lane >> 5);
                            int tcol = n_off + nj * 32 + (lane & 31);
                            float d = fmaxf(sQ2[qrow] - 2.0f * acc[g][nj][r] + sT2[tcol], 0.0f);
                            key = ((u64)__float_as_uint(d) << 16) | (u64)(u32)(tb + tcol);
                            want = key < kth64[qrow];
                        }
                        u64 vote = __ballot(want);
                        if (vote) {
                            u32 lo = (u32)vote, hi = (u32)(vote >> 32);
                            u32 myBase = 0;
                            if (lane == 0 && lo)  myBase = atomicAdd(&cnt[qlo], __popc(lo));
                            if (lane == 32 && hi) myBase = atomicAdd(&cnt[qlo + 4], __popc(hi));
                            u32 b0 = (u32)__shfl((int)myBase, 0);
                            u32 b1 = (u32)__shfl((int)myBase, 32);
                            if (want) {
                                u32 half = (lane < 32) ? lo : hi;
                                u32 hl = lane & 31;
                                u32 idxin = __popc(half & ((1u << hl) - 1u));
                                u32 slot = ((lane < 32) ? b0 : b1) + idxin;
                                if (slot < MCAP) { buf[qrow * MCAP + slot] = key; mask |= (1ULL << bit); }
                            }
                        }
                    }
                }
                __syncthreads();  // buf/cnt complete
                // insert: thread tid owns query tid (eligible for this group)
                if (tid < MQT && ((tid >> 5) & 1) == g) {
                    u32 n = cnt[tid];
                    u32 m = n < MCAP ? n : MCAP;
                    for (u32 e = 0; e < m; ++e) {
                        u64 key = buf[tid * MCAP + e];
                        u64 last = ((u64)topkD[tid][KNN - 1] << 16) | topkI[tid][KNN - 1];
                        if (key < last) {
                            int p = KNN - 1;
                            while (p > 0) {
                                u64 prev = ((u64)topkD[tid][p - 1] << 16) | topkI[tid][p - 1];
                                if (prev > key) {
                                    topkD[tid][p] = topkD[tid][p - 1];
                                    topkI[tid][p] = topkI[tid][p - 1];
                                    --p;
                                } else break;
                            }
                            topkD[tid][p] = (u32)(key >> 16);
                            topkI[tid][p] = (u16)(key & 0xFFFF);
                        }
                    }
                    // clamp to seed: a non-full list's ~0 sentinel must NOT widen the filter
                    u64 last = ((u64)topkD[tid][KNN - 1] << 16) | topkI[tid][KNN - 1];
                    kth64[tid] = last < seedkey ? last : seedkey;
                    if (n > MCAP) againF = 1;
                    cnt[tid] = 0u;
                }
                __syncthreads();  // insert done, againF final, kth updated
                int go = againF;
                __syncthreads();  // all reads of againF done
                if (tid == 0) againF = 0;
                if (!go) break;   // uniform
                __syncthreads();  // reset visible before next pass's insert
            }
        }
    }

    __syncthreads();
    for (int i = tid; i < MQT * KNN; i += 256) {
        int q = i >> 5, k = i & 31;
        u64 key = ((u64)topkD[q][k] << 16) | topkI[q][k];
        cand[((size_t)(q0 + q) * NS + blockIdx.x) * KNN + k] = key;
    }
}

// ---------------- fallback: fp32 distance + per-slice top-K (R2, proven) ----------------
__launch_bounds__(256, 4)
__global__ void knn_part(const float* __restrict__ Xq, const float* __restrict__ Xt,
                         const float* __restrict__ q2, const float* __restrict__ t2,
                         u64* __restrict__ cand) {
    __shared__ float sQ[KK][QT];
    __shared__ float sT[KK][TT];
    __shared__ u64 topk[QT][KNN];
    __shared__ u64 buf[QT][FCAP];
    __shared__ u64 kth64[QT];
    __shared__ u32 cnt[QT];
    __shared__ int againF;

    const int tid = threadIdx.x;
    const int q0 = blockIdx.x * QT;
    const int t0 = blockIdx.y * SLICE;
    const int tq4 = (tid >> 5) * 4;
    const int tt4 = (tid & 31) * 4;
    const int pg = tid & 63;
    const int kg = tid >> 6;
    const int qp = tid & 31;
    const int kq = tid >> 5;

    for (int i = tid; i < QT * KNN; i += 256) ((u64*)topk)[i] = ~0ULL;
    if (tid < QT) { kth64[tid] = ~0ULL; cnt[tid] = 0u; }
    if (tid == 0) againF = 0;

    float qq[4];
    #pragma unroll
    for (int i = 0; i < 4; ++i) qq[i] = q2[q0 + tq4 + i];

    for (int chunk = 0; chunk < SLICE / TT; ++chunk) {
        const int tbase = t0 + chunk * TT;
        float acc[4][8];
        #pragma unroll
        for (int i = 0; i < 4; ++i)
            #pragma unroll
            for (int j = 0; j < 8; ++j) acc[i][j] = 0.f;

        for (int k0 = 0; k0 < DIM; k0 += KK) {
            __syncthreads();
            {
                const float* Tp = Xt + (size_t)(tbase + pg * 4) * DIM + k0 + kg * 4;
                float4 r0 = *(const float4*)(Tp);
                float4 r1 = *(const float4*)(Tp + DIM);
                float4 r2 = *(const float4*)(Tp + 2 * DIM);
                float4 r3 = *(const float4*)(Tp + 3 * DIM);
                *(float4*)&sT[kg * 4 + 0][pg * 4] = make_float4(r0.x, r1.x, r2.x, r3.x);
                *(float4*)&sT[kg * 4 + 1][pg * 4] = make_float4(r0.y, r1.y, r2.y, r3.y);
                *(float4*)&sT[kg * 4 + 2][pg * 4] = make_float4(r0.z, r1.z, r2.z, r3.z);
                *(float4*)&sT[kg * 4 + 3][pg * 4] = make_float4(r0.w, r1.w, r2.w, r3.w);
            }
            {
                float2 v = *(const float2*)(Xq + (size_t)(q0 + qp) * DIM + k0 + kq * 2);
                sQ[kq * 2 + 0][qp] = v.x;
                sQ[kq * 2 + 1][qp] = v.y;
            }
            __syncthreads();
            #pragma unroll
            for (int k = 0; k < KK; ++k) {
                float4 qv = *(const float4*)&sQ[k][tq4];
                float4 ta = *(const float4*)&sT[k][tt4];
                float4 tb = *(const float4*)&sT[k][128 + tt4];
                float qa[4] = {qv.x, qv.y, qv.z, qv.w};
                float tv[8] = {ta.x, ta.y, ta.z, ta.w, tb.x, tb.y, tb.z, tb.w};
                #pragma unroll
                for (int i = 0; i < 4; ++i)
                    #pragma unroll
                    for (int j = 0; j < 8; ++j)
                        acc[i][j] = fmaf(qa[i], tv[j], acc[i][j]);
            }
        }

        float t2v[8];
        #pragma unroll
        for (int j = 0; j < 4; ++j) {
            t2v[j]     = t2[tbase + tt4 + j];
            t2v[4 + j] = t2[tbase + 128 + tt4 + j];
        }
        #pragma unroll
        for (int i = 0; i < 4; ++i)
            #pragma unroll
            for (int j = 0; j < 8; ++j)
                acc[i][j] = fmaxf((qq[i] - 2.f * acc[i][j]) + t2v[j], 0.f);

        unsigned mask = 0;
        for (;;) {
            u64 kv[4];
            #pragma unroll
            for (int i = 0; i < 4; ++i) kv[i] = kth64[tq4 + i];
            #pragma unroll
            for (int i = 0; i < 4; ++i) {
                #pragma unroll
                for (int j = 0; j < 8; ++j) {
                    unsigned b = 1u << (i * 8 + j);
                    if (mask & b) continue;
                    int tloc = (j < 4) ? (tt4 + j) : (128 + tt4 + (j - 4));
                    u64 key = ((u64)__float_as_uint(acc[i][j]) << 16) |
                              (u64)(unsigned)(tbase + tloc);
                    if (key < kv[i]) {
                        unsigned pos = atomicAdd(&cnt[tq4 + i], 1u);
                        if (pos < FCAP) { buf[tq4 + i][pos] = key; mask |= b; }
                    }
                }
            }
            __syncthreads();
            if (tid < QT) {
                unsigned n = cnt[tid];
                unsigned m = n < FCAP ? n : FCAP;
                for (unsigned e = 0; e < m; ++e) {
                    u64 key = buf[tid][e];
                    if (key < topk[tid][KNN - 1]) {
                        int p = KNN - 1;
                        while (p > 0 && topk[tid][p - 1] > key) {
                            topk[tid][p] = topk[tid][p - 1];
                            --p;
                        }
                        topk[tid][p] = key;
                    }
                }
                kth64[tid] = topk[tid][KNN - 1];
                if (n > FCAP) againF = 1;
                cnt[tid] = 0u;
            }
            __syncthreads();
            int go = againF;
            __syncthreads();
            if (tid == 0) againF = 0;
            if (!go) break;
            __syncthreads();
        }
    }

    __syncthreads();
    for (int i = tid; i < QT * KNN; i += 256) {
        int q = i >> 5, k = i & 31;
        cand[((size_t)(q0 + q) * NS + blockIdx.y) * KNN + k] = topk[q][k];
    }
}

// ---------------- merge + vote ----------------
__global__ void knn_merge(const u64* __restrict__ cand,
                          const int* __restrict__ y_train, int* __restrict__ out) {
    __shared__ u64 keys[NS * KNN];
    __shared__ u64 top[KNN];
    __shared__ int counts[NC];
    int q = blockIdx.x;
    for (int i = threadIdx.x; i < NS * KNN; i += 64)
        keys[i] = cand[(size_t)q * NS * KNN + i];
    for (int i = threadIdx.x; i < NC; i += 64) counts[i] = 0;
    if (threadIdx.x < KNN) top[threadIdx.x] = ~0ULL;
    __syncthreads();

    if (threadIdx.x == 0) {
        for (int s = 0; s < NS; ++s) {
            for (int j = 0; j < KNN; ++j) {
                u64 key = keys[s * KNN + j];
                if (key >= top[KNN - 1]) break;
                int p = KNN - 1;
                while (p > 0 && top[p - 1] > key) { top[p] = top[p - 1]; --p; }
                top[p] = key;
            }
        }
        for (int k = 0; k < KNN; ++k) {
            int idx = (int)(top[k] & 0xFFFF);
            counts[y_train[idx]]++;
        }
        int bestc = counts[0], bestl = 0;
        for (int c = 1; c < NC; ++c)
            if (counts[c] > bestc) { bestc = counts[c]; bestl = c; }
        out[q] = bestl;
    }
}

extern "C" void kernel_launch(void* const* d_in, const int* in_sizes, int n_in,
                              void* d_out, int out_size, void* d_ws, size_t ws_size,
                              hipStream_t stream) {
    const float* Xq = (const float*)d_in[0];   // [2048, 512]
    const float* Xt = (const float*)d_in[1];   // [65536, 512]
    const int*   y  = (const int*)d_in[2];     // [65536]
    int* out = (int*)d_out;                    // [2048] int32

    float* t2 = (float*)d_ws;                                   // 256 KB
    float* q2 = t2 + NT;                                        // 8 KB
    u64* cand = (u64*)(q2 + NQ);                                // 16.8 MB
    u32* seed = (u32*)(cand + (size_t)NQ * NS * KNN);           // 8 KB
    u16* Qh = (u16*)(seed + NQ);                                // 2 MB
    u16* Ql = Qh + (size_t)NQ * DIM;                            // 2 MB
    u16* Th = Ql + (size_t)NQ * DIM;                            // 64 MB
    u16* Tl = Th + (size_t)NT * DIM;                            // 64 MB
    const size_t need = (size_t)(NT + NQ) * 4
                      + (size_t)NQ * NS * KNN * 8
                      + (size_t)NQ * 4
                      + 2 * ((size_t)NQ * DIM + (size_t)NT * DIM) * 2;  // ~148.3 MB
    const bool use_mfma = ws_size >= need;

    norm_kernel<<<NT / 4, 256, 0, stream>>>(Xt, t2, NT);
    norm_kernel<<<NQ / 4, 256, 0, stream>>>(Xq, q2, NQ);
    if (use_mfma) {
        hipMemsetAsync(seed, 0xFF, NQ * sizeof(u32), stream);
        split_kernel<<<(NQ * DIM / 4 + 255) / 256, 256, 0, stream>>>(Xq, Qh, Ql, NQ * DIM / 4);
        split_kernel<<<(NT * DIM / 4 + 255) / 256, 256, 0, stream>>>(Xt, Th, Tl, NT * DIM / 4);
        knn_prepass<<<dim3(NQ / PQT, NTPRE / PSLICE), 256, 0, stream>>>(Xq, Xt, q2, t2, seed);
        knn_mfma<<<dim3(NT / MSLICE, NQ / MQT), 256, 0, stream>>>(Qh, Ql, Th, Tl, q2, t2, seed, cand);
    } else {
        knn_part<<<dim3(NQ / QT, NS), 256, 0, stream>>>(Xq, Xt, q2, t2, cand);
    }
    knn_merge<<<NQ, 64, 0, stream>>>(cand, y, out);
}